// Round 16
// baseline (128.899 us; speedup 1.0000x reference)
//
#include <hip/hip_runtime.h>
#include <hip/hip_bf16.h>

typedef __bf16 bf16x8 __attribute__((ext_vector_type(8)));
typedef __bf16 bf16x4 __attribute__((ext_vector_type(4)));
typedef float  f32x4  __attribute__((ext_vector_type(4)));
typedef unsigned __attribute__((may_alias)) u32a;

#define MFMA_B16(a, b, c) __builtin_amdgcn_mfma_f32_16x16x32_bf16((a), (b), (c), 0, 0, 0)

static constexpr int Bk  = 4;
static constexpr int Sk  = 1024;
static constexpr int Dk  = 1024;
static constexpr int Hk  = 16;
static constexpr int DHk = 64;

// ws layout (__bf16 elements)
static constexpr size_t QH_OFF = 0;                 // [64][1024][64]
static constexpr size_t K_OFF  = 4194304;           // [64][1024][64]
static constexpr size_t VT_OFF = 8388608;           // [64][64][1024]
static constexpr size_t WT_OFF = 12582912;           // [3][1024][1024]
static constexpr size_t ER_OFF = 15728640;           // [1104][64] (80 zero-pad rows)
static constexpr size_t WS_ELEMS = 15799296;

__device__ __forceinline__ void load_lds16(const void* g, void* l) {
    __builtin_amdgcn_global_load_lds((const __attribute__((address_space(1))) void*)g,
                                     (__attribute__((address_space(3))) void*)l, 16, 0, 0);
}

// DPP cross-lane on the VALU pipe (no LDS). CTRL: 0x12N = row_ror:N, 0xB1 = quad_perm xor1.
template<int CTRL>
__device__ __forceinline__ float dppf(float x) {
    int v = __builtin_bit_cast(int, x);
    return __builtin_bit_cast(float,
        __builtin_amdgcn_update_dpp(v, v, CTRL, 0xF, 0xF, false));
}
__device__ __forceinline__ float rmax16(float x) {   // max over the 16-lane row
    x = fmaxf(x, dppf<0x128>(x));
    x = fmaxf(x, dppf<0x124>(x));
    x = fmaxf(x, dppf<0x122>(x));
    x = fmaxf(x, dppf<0x121>(x));
    return x;
}
__device__ __forceinline__ float rsum16(float x) {   // sum over the 16-lane row
    x += dppf<0x128>(x);
    x += dppf<0x124>(x);
    x += dppf<0x122>(x);
    x += dppf<0x121>(x);
    return x;
}
__device__ __forceinline__ unsigned pk_bf16(float lo, float hi) {
    unsigned r;
    asm("v_cvt_pk_bf16_f32 %0, %1, %2" : "=v"(r) : "v"(lo), "v"(hi));
    return r;
}

// ---------------- prep: W -> Wt (bf16, transposed), Er -> bf16 (+80 zero rows) ----------------
__global__ void prep_kernel(const float* __restrict__ Wq, const float* __restrict__ Wk,
                            const float* __restrict__ Wv, const float* __restrict__ Er,
                            __bf16* __restrict__ wt, __bf16* __restrict__ erb)
{
    __shared__ float tile[64][65];
    const int z = blockIdx.z;
    const int tid = threadIdx.x;
    if (z == 3) {
        int idx = (blockIdx.y * 16 + blockIdx.x) * 256 + tid;   // 0..65535
        erb[idx] = (__bf16)Er[idx];
        if (idx < 5120) erb[65536 + idx] = (__bf16)0.f;         // zero-pad rows 1024..1103
        return;
    }
    const float* W = (z == 0) ? Wq : (z == 1 ? Wk : Wv);
    __bf16* dst = wt + (size_t)z * Dk * Dk;
    const int k0 = blockIdx.y * 64, n0 = blockIdx.x * 64;
    #pragma unroll
    for (int j = 0; j < 16; ++j) {
        int idx = tid + j * 256; int r = idx >> 6, c = idx & 63;
        tile[r][c] = W[(size_t)(k0 + r) * Dk + n0 + c];
    }
    __syncthreads();
    #pragma unroll
    for (int j = 0; j < 16; ++j) {
        int idx = tid + j * 256; int r = idx >> 6, c = idx & 63;
        dst[(size_t)(n0 + r) * Dk + k0 + c] = (__bf16)tile[c][r];   // Wt[n][k] = W[k][n]
    }
}

// ---------------- projections: m97-style 128x128 tile, BK=32, global_load_lds ----------------
__global__ __launch_bounds__(256) void proj_kernel(
    const float* __restrict__ Xq, const float* __restrict__ Xkv,
    const float* __restrict__ bq, const float* __restrict__ bk,
    const float* __restrict__ bv, const __bf16* __restrict__ wt,
    __bf16* __restrict__ qh, __bf16* __restrict__ kws, __bf16* __restrict__ vt)
{
    __shared__ __align__(16) float  Al[128 * 32];
    __shared__ __align__(16) __bf16 Bl[128 * 32];

    const int z = blockIdx.z;
    const float* X    = (z == 0) ? Xq : Xkv;
    const float* bias = (z == 0) ? bq : (z == 1 ? bk : bv);
    const __bf16* Wz  = wt + (size_t)z * Dk * Dk;

    const int m0   = blockIdx.x * 128;
    const int n0   = blockIdx.y * 128;
    const int tid  = threadIdx.x;
    const int lane = tid & 63;
    const int w    = tid >> 6;
    const int wr   = w >> 1, wc = w & 1;
    const int l15  = lane & 15;
    const int g    = lane >> 4;

    const float* asrc[4];
    int adst[4];
    #pragma unroll
    for (int i = 0; i < 4; ++i) {
        const int c = w * 4 + i;
        asrc[i] = X + (size_t)(m0 + c * 8 + (lane >> 3)) * Dk + (((lane & 7) ^ (lane >> 3)) << 2);
        adst[i] = c * 1024 + lane * 16;          // bytes
    }
    const __bf16* bsrc[2];
    int bdst[2];
    #pragma unroll
    for (int i = 0; i < 2; ++i) {
        const int c = w * 2 + i;
        bsrc[i] = Wz + (size_t)(n0 + c * 16 + (lane >> 2)) * Dk + (((lane & 3) ^ ((lane >> 3) & 3)) << 3);
        bdst[i] = c * 1024 + lane * 16;          // bytes
    }

    int aoff0[4], aoff1[4], boff[4];
    #pragma unroll
    for (int m = 0; m < 4; ++m) {
        const int row = wr * 64 + m * 16 + l15;          // row&7 == l15&7
        aoff0[m] = row * 128 + (((2 * g)     ^ (l15 & 7)) << 4);
        aoff1[m] = row * 128 + (((2 * g + 1) ^ (l15 & 7)) << 4);
    }
    #pragma unroll
    for (int n = 0; n < 4; ++n) {
        const int row = wc * 64 + n * 16 + l15;          // (row>>1)&3 == (l15>>1)&3
        boff[n] = row * 64 + ((g ^ ((l15 >> 1) & 3)) << 4);
    }

    const f32x4 fz = {0.f, 0.f, 0.f, 0.f};
    f32x4 acc[4][4];
    #pragma unroll
    for (int m = 0; m < 4; ++m)
        #pragma unroll
        for (int n = 0; n < 4; ++n) acc[m][n] = fz;

    const char* Alc = (const char*)Al;
    const char* Blc = (const char*)Bl;

    for (int ks = 0; ks < Dk / 32; ++ks) {
        #pragma unroll
        for (int i = 0; i < 4; ++i)
            load_lds16(asrc[i], (char*)Al + adst[i]);
        #pragma unroll
        for (int i = 0; i < 2; ++i)
            load_lds16(bsrc[i], (char*)Bl + bdst[i]);
        #pragma unroll
        for (int i = 0; i < 4; ++i) asrc[i] += 32;
        #pragma unroll
        for (int i = 0; i < 2; ++i) bsrc[i] += 32;
        __syncthreads();

        bf16x8 bf[4];
        #pragma unroll
        for (int n = 0; n < 4; ++n)
            bf[n] = *(const bf16x8*)(Blc + boff[n]);
        bf16x8 af[4];
        #pragma unroll
        for (int m = 0; m < 4; ++m) {
            f32x4 x0 = *(const f32x4*)(Alc + aoff0[m]);
            f32x4 x1 = *(const f32x4*)(Alc + aoff1[m]);
            bf16x8 a;
            a[0] = (__bf16)x0[0]; a[1] = (__bf16)x0[1]; a[2] = (__bf16)x0[2]; a[3] = (__bf16)x0[3];
            a[4] = (__bf16)x1[0]; a[5] = (__bf16)x1[1]; a[6] = (__bf16)x1[2]; a[7] = (__bf16)x1[3];
            af[m] = a;
        }

        #pragma unroll
        for (int m = 0; m < 4; ++m)
            #pragma unroll
            for (int n = 0; n < 4; ++n)
                acc[m][n] = MFMA_B16(af[m], bf[n], acc[m][n]);
        __syncthreads();
    }

    #pragma unroll
    for (int n = 0; n < 4; ++n) {
        const float bb = bias[n0 + wc * 64 + n * 16 + l15];
        #pragma unroll
        for (int m = 0; m < 4; ++m)
            #pragma unroll
            for (int r = 0; r < 4; ++r) acc[m][n][r] += bb;
    }

    const int b   = m0 >> 10;
    const int s0t = (m0 & 1023) + wr * 64;
    const int h   = (n0 + wc * 64) >> 6;

    if (z < 2) {
        __bf16* dst = (z == 0) ? qh : kws;
        const size_t rowbase = (size_t)(b * Hk + h) * Sk;
        #pragma unroll
        for (int m = 0; m < 4; ++m) {
            #pragma unroll
            for (int r = 0; r < 4; ++r) {
                const int s = s0t + m * 16 + g * 4 + r;
                __bf16* drow = dst + (rowbase + s) * DHk;
                #pragma unroll
                for (int n = 0; n < 4; ++n)
                    drow[n * 16 + l15] = (__bf16)acc[m][n][r];
            }
        }
    } else {
        const size_t hb = (size_t)(b * Hk + h) * DHk;
        #pragma unroll
        for (int m = 0; m < 4; ++m) {
            const int sb = s0t + m * 16 + g * 4;
            #pragma unroll
            for (int n = 0; n < 4; ++n) {
                const int dh = n * 16 + l15;
                bf16x4 pk;
                #pragma unroll
                for (int r = 0; r < 4; ++r) pk[r] = (__bf16)acc[m][n][r];
                *(bf16x4*)(vt + (hb + dh) * Sk + sb) = pk;
            }
        }
    }
}

// ---------------- fused causal attention with relative-position band ----------------
// Base = R13 (best: 69 us attn). R14/R15 pipeline variants refuted (+6-7 us).
// This round, two low-risk cuts:
//  - V read DIRECT from global (m169: staging L2-resident data is overhead).
//    V per bh = 128KB, 8 bh/XCD = 2MB < 4MB L2 -> warm. The 8 V loads issue
//    pre-barrier with Er; skew+QK+G (~800 cyc) hides their latency before PV.
//    Removes V staging + 8 ds_reads/step; LDS 40KB -> 24KB.
//  - erb zero-padded to 1104 rows: jr clamp dropped (rows >=1024 are causally
//    masked), Er addressing via one walking base pointer (+4096 elems/iter).
// Keeps: (256,3) envelope, single barrier/step, K dbuf via global_load_lds,
// DPP softmax, cvt_pk P-pack, stride-64 XOR P_lds, defer-max, heavy-first
// dispatch, bh%8 XCD locality.
__global__ __launch_bounds__(256, 3) void attn_kernel(
    const __bf16* __restrict__ qh, const __bf16* __restrict__ kws,
    const __bf16* __restrict__ vt, const __bf16* __restrict__ erb,
    float* __restrict__ out)
{
    __shared__ __align__(16) __bf16 Kl[2][4096];     // [buf][64 s][64 dh], swizzled
    __shared__ __align__(16) __bf16 P_lds[4][16][64];// stride 64, XOR-swizzled

    const int tid  = threadIdx.x;
    const int lane = tid & 63;
    const int w    = tid >> 6;
    const int l15  = lane & 15;
    const int g    = lane >> 4;

    const int lid   = blockIdx.x;        // 0..1023
    const int bh    = lid & 63;          // lid%8 == bh%8 -> one bh's blocks share an XCD
    const int strip = 15 - (lid >> 6);   // heavy strips (16 tiles) dispatch first
    const int ntw   = strip + 1;
    const int sw    = strip * 64 + w * 16;

    const __bf16* kbase = kws + (size_t)bh * Sk * DHk;
    const __bf16* vbase = vt  + (size_t)bh * DHk * Sk;
    const __bf16* qbase = qh  + ((size_t)bh * Sk + sw) * DHk;

    __bf16 (*Pw)[64] = P_lds[w];

    // K staging geometry: thread covers rows {trow, trow+32}, lds slot tslot,
    // source col-slot = tslot ^ (row&7)  (row&7 == trow&7)
    const int trow   = tid >> 3;
    const int tslot  = tid & 7;
    const int srcoff = (tslot ^ (trow & 7)) << 3;    // element offset (8 bf16 / slot)
    char* kd0 = (char*)Kl + tid * 16;                // dest byte == row*128 + slot*16

    bf16x8 aq[2];
    aq[0] = *(const bf16x8*)(qbase + l15 * DHk + g * 8);
    aq[1] = *(const bf16x8*)(qbase + l15 * DHk + 32 + g * 8);

    const f32x4 fz = {0.f, 0.f, 0.f, 0.f};
    f32x4 O[4];
    float m_[4], l_[4];
    #pragma unroll
    for (int n = 0; n < 4; ++n) O[n] = fz;
    #pragma unroll
    for (int r = 0; r < 4; ++r) { m_[r] = -1e30f; l_[r] = 0.f; }

    const float SCL = 0.125f * 1.44269504088896f;    // 1/sqrt(DH) * log2(e)

    // Er walking base (rows >= 1024 are zero-padded, no clamp needed)
    const __bf16* ecp = erb + (size_t)(1008 - sw + l15) * DHk + g * 8;

    // ---- prologue: stage K tile 0 into buffer 0 ----
    load_lds16(kbase + (size_t)trow * DHk + srcoff,        kd0);
    load_lds16(kbase + (size_t)(32 + trow) * DHk + srcoff, kd0 + 4096);
    __builtin_amdgcn_sched_barrier(0);
    asm volatile("s_waitcnt vmcnt(0)" ::: "memory");
    __builtin_amdgcn_sched_barrier(0);
    __builtin_amdgcn_s_barrier();
    __builtin_amdgcn_sched_barrier(0);

    for (int it = 0; it < ntw; ++it) {
        const int t0  = it * 64;
        const int cur = it & 1;

        // my K stage ops for buf[cur] (issued one full iteration ago) retired
        __builtin_amdgcn_sched_barrier(0);
        asm volatile("s_waitcnt vmcnt(0)" ::: "memory");
        __builtin_amdgcn_sched_barrier(0);

        // ---- Er loads (10) + V loads (8), register targets — in flight ACROSS
        //      the barrier; latency hides under barrier-sync + QK^T + G ----
        bf16x8 ec[10];
        #pragma unroll
        for (int kt = 0; kt < 2; ++kt)
            #pragma unroll
            for (int jj = 0; jj < 5; ++jj)
                ec[kt * 5 + jj] = *(const bf16x8*)(ecp + jj * 16 * DHk + kt * 32);
        bf16x8 vb[8];
        #pragma unroll
        for (int kt = 0; kt < 2; ++kt)
            #pragma unroll
            for (int n = 0; n < 4; ++n)
                vb[kt * 4 + n] = *(const bf16x8*)(vbase + (size_t)(n * 16 + l15) * Sk + t0 + kt * 32 + g * 8);

        __builtin_amdgcn_sched_barrier(0);
        __builtin_amdgcn_s_barrier();            // publishes K[cur]; K[cur^1] free
        __builtin_amdgcn_sched_barrier(0);

        if (it + 1 < ntw) {
            const int t0n = t0 + 64;
            char* kd = kd0 + (cur ^ 1) * 8192;
            load_lds16(kbase + (size_t)(t0n + trow) * DHk + srcoff,      kd);
            load_lds16(kbase + (size_t)(t0n + 32 + trow) * DHk + srcoff, kd + 4096);
        }

        const char* Kc = (const char*)Kl + cur * 8192;

        // ---- QK^T from LDS (swizzled ds_read_b128) ----
        f32x4 sc[4];
        #pragma unroll
        for (int j = 0; j < 4; ++j) sc[j] = fz;
        #pragma unroll
        for (int kt = 0; kt < 2; ++kt) {
            bf16x8 kb[4];
            #pragma unroll
            for (int j = 0; j < 4; ++j)
                kb[j] = *(const bf16x8*)(Kc + (j * 16 + l15) * 128 + ((((kt << 2) | g) ^ (l15 & 7)) << 4));
            __builtin_amdgcn_s_setprio(1);
            #pragma unroll
            for (int j = 0; j < 4; ++j)
                sc[j] = MFMA_B16(aq[kt], kb[j], sc[j]);
            __builtin_amdgcn_s_setprio(0);
        }

        // ---- G = Q @ Er^T over the 80-wide band ----
        f32x4 gf[5];
        #pragma unroll
        for (int jj = 0; jj < 5; ++jj) gf[jj] = fz;
        __builtin_amdgcn_s_setprio(1);
        #pragma unroll
        for (int kt = 0; kt < 2; ++kt)
            #pragma unroll
            for (int jj = 0; jj < 5; ++jj)
                gf[jj] = MFMA_B16(aq[kt], ec[kt * 5 + jj], gf[jj]);
        __builtin_amdgcn_s_setprio(0);

        // ---- skew via shuffle + scale (exp2 domain) + causal mask ----
        #pragma unroll
        for (int r = 0; r < 4; ++r) {
            const int rr  = g * 4 + r;
            const int sft = 15 - rr;
            const int src = (g << 4) + ((l15 + sft) & 15);   // absolute lane in wave
            const bool hi = (l15 + sft) >= 16;
            float h[5];
            #pragma unroll
            for (int jj = 0; jj < 5; ++jj) h[jj] = __shfl(gf[jj][r], src);
            const int s = sw + rr;
            #pragma unroll
            for (int j = 0; j < 4; ++j) {
                float gval = hi ? h[j + 1] : h[j];
                float v = (sc[j][r] + gval) * SCL;
                int t = t0 + j * 16 + l15;
                sc[j][r] = (t > s) ? -1e30f : v;
            }
        }

        // ---- online softmax: DPP row reduces (VALU pipe), defer-max ----
        float mt[4];
        #pragma unroll
        for (int r = 0; r < 4; ++r)
            mt[r] = rmax16(fmaxf(fmaxf(sc[0][r], sc[1][r]), fmaxf(sc[2][r], sc[3][r])));

        bool grow = (mt[0] > m_[0] + 8.f) || (mt[1] > m_[1] + 8.f) ||
                    (mt[2] > m_[2] + 8.f) || (mt[3] > m_[3] + 8.f);
        if (__any(grow)) {
            #pragma unroll
            for (int r = 0; r < 4; ++r) {
                float mnew = fmaxf(m_[r], mt[r]);
                float scl  = exp2f(m_[r] - mnew);
                l_[r] *= scl;
                m_[r]  = mnew;
                #pragma unroll
                for (int n = 0; n < 4; ++n) O[n][r] *= scl;
            }
        }
        #pragma unroll
        for (int r = 0; r < 4; ++r) {
            float rs = 0.f;
            #pragma unroll
            for (int j = 0; j < 4; ++j) {
                float p = exp2f(sc[j][r] - m_[r]);
                sc[j][r] = p; rs += p;
            }
            l_[r] += rsum16(rs);
        }

        // ---- P -> LDS packed b32, XOR-swizzled stride-64 rows ----
        {
            const int p01 = l15 & 1;
            #pragma unroll
            for (int j = 0; j < 4; ++j) {
                const int slot = 2 * j + (l15 >> 3);
                #pragma unroll
                for (int h2 = 0; h2 < 2; ++h2) {
                    float a0 = sc[j][h2];
                    float a2 = sc[j][h2 + 2];
                    float b0 = dppf<0xB1>(a0);       // partner lane's row-h2 value
                    float b2 = dppf<0xB1>(a2);       // partner lane's row-h2+2 value
                    float lo = p01 ? b2 : a0;
                    float hi = p01 ? a2 : b0;
                    unsigned wd = pk_bf16(lo, hi);
                    const int row = g * 4 + h2 + (p01 ? 2 : 0);
                    const int byteoff = row * 128 + (((slot ^ (row & 7)) << 4) | ((l15 & 6) << 1));
                    *(u32a*)((char*)Pw + byteoff) = wd;
                }
            }
        }
        asm volatile("" ::: "memory");
        __builtin_amdgcn_sched_barrier(0);

        // ---- PV: V from registers (direct global), P from LDS with same XOR ----
        __builtin_amdgcn_s_setprio(1);
        #pragma unroll
        for (int kt = 0; kt < 2; ++kt) {
            bf16x8 pa = *(const bf16x8*)((const char*)Pw + l15 * 128 +
                                         ((((kt << 2) | g) ^ (l15 & 7)) << 4));
            #pragma unroll
            for (int n = 0; n < 4; ++n)
                O[n] = MFMA_B16(pa, vb[kt * 4 + n], O[n]);
        }
        __builtin_amdgcn_s_setprio(0);

        ecp += 64 * DHk;                         // band shifts by 64 rows per tile
    }

    // ---- normalize + write out [b][s][h*64+dh] ----
    const int b = bh >> 4, h = bh & 15;
    float* obase = out + ((size_t)b * Sk + sw) * Dk + h * DHk;
    #pragma unroll
    for (int r = 0; r < 4; ++r) {
        float inv = 1.f / l_[r];
        #pragma unroll
        for (int n = 0; n < 4; ++n)
            obase[(size_t)(g * 4 + r) * Dk + n * 16 + l15] = O[n][r] * inv;
    }
}

extern "C" void kernel_launch(void* const* d_in, const int* in_sizes, int n_in,
                              void* d_out, int out_size, void* d_ws, size_t ws_size,
                              hipStream_t stream)
{
    const float* q  = (const float*)d_in[0];
    const float* kv = (const float*)d_in[1];
    const float* Wq = (const float*)d_in[2];
    const float* bq = (const float*)d_in[3];
    const float* Wk = (const float*)d_in[4];
    const float* bk = (const float*)d_in[5];
    const float* Wv = (const float*)d_in[6];
    const float* bv = (const float*)d_in[7];
    const float* Er = (const float*)d_in[8];
    float* out = (float*)d_out;

    if (ws_size < WS_ELEMS * sizeof(__bf16)) return;
    __bf16* ws  = (__bf16*)d_ws;
    __bf16* qh  = ws + QH_OFF;
    __bf16* kws = ws + K_OFF;
    __bf16* vt  = ws + VT_OFF;
    __bf16* wt  = ws + WT_OFF;
    __bf16* erb = ws + ER_OFF;

    prep_kernel<<<dim3(16, 16, 4), 256, 0, stream>>>(Wq, Wk, Wv, Er, wt, erb);
    proj_kernel<<<dim3(32, 8, 3), 256, 0, stream>>>(q, kv, bq, bk, bv, wt, qh, kws, vt);
    attn_kernel<<<dim3(1024), 256, 0, stream>>>(qh, kws, vt, erb, out);
}

// Round 17
// 102.038 us; speedup vs baseline: 1.2632x; 1.2632x over previous
//
#include <hip/hip_runtime.h>
#include <hip/hip_bf16.h>

typedef __bf16 bf16x8 __attribute__((ext_vector_type(8)));
typedef __bf16 bf16x4 __attribute__((ext_vector_type(4)));
typedef float  f32x4  __attribute__((ext_vector_type(4)));
typedef unsigned __attribute__((may_alias)) u32a;

#define MFMA_B16(a, b, c) __builtin_amdgcn_mfma_f32_16x16x32_bf16((a), (b), (c), 0, 0, 0)

static constexpr int Bk  = 4;
static constexpr int Sk  = 1024;
static constexpr int Dk  = 1024;
static constexpr int Hk  = 16;
static constexpr int DHk = 64;

// ws layout (__bf16 elements)
static constexpr size_t QH_OFF = 0;                 // [64][1024][64]
static constexpr size_t K_OFF  = 4194304;           // [64][1024][64]
static constexpr size_t VT_OFF = 8388608;           // [64][64][1024]
static constexpr size_t WT_OFF = 12582912;          // [3][1024][1024]
static constexpr size_t ER_OFF = 15728640;          // [1024][64]
static constexpr size_t WS_ELEMS = 15794176;

__device__ __forceinline__ void load_lds16(const void* g, void* l) {
    __builtin_amdgcn_global_load_lds((const __attribute__((address_space(1))) void*)g,
                                     (__attribute__((address_space(3))) void*)l, 16, 0, 0);
}

// DPP cross-lane on the VALU pipe (no LDS). CTRL: 0x12N = row_ror:N, 0xB1 = quad_perm xor1.
template<int CTRL>
__device__ __forceinline__ float dppf(float x) {
    int v = __builtin_bit_cast(int, x);
    return __builtin_bit_cast(float,
        __builtin_amdgcn_update_dpp(v, v, CTRL, 0xF, 0xF, false));
}
__device__ __forceinline__ float rmax16(float x) {   // max over the 16-lane row
    x = fmaxf(x, dppf<0x128>(x));
    x = fmaxf(x, dppf<0x124>(x));
    x = fmaxf(x, dppf<0x122>(x));
    x = fmaxf(x, dppf<0x121>(x));
    return x;
}
__device__ __forceinline__ float rsum16(float x) {   // sum over the 16-lane row
    x += dppf<0x128>(x);
    x += dppf<0x124>(x);
    x += dppf<0x122>(x);
    x += dppf<0x121>(x);
    return x;
}
__device__ __forceinline__ unsigned pk_bf16(float lo, float hi) {
    unsigned r;
    asm("v_cvt_pk_bf16_f32 %0, %1, %2" : "=v"(r) : "v"(lo), "v"(hi));
    return r;
}

// ---------------- prep: W -> Wt (bf16, transposed), Er -> bf16 ----------------
__global__ void prep_kernel(const float* __restrict__ Wq, const float* __restrict__ Wk,
                            const float* __restrict__ Wv, const float* __restrict__ Er,
                            __bf16* __restrict__ wt, __bf16* __restrict__ erb)
{
    __shared__ float tile[64][65];
    const int z = blockIdx.z;
    const int tid = threadIdx.x;
    if (z == 3) {
        int idx = (blockIdx.y * 16 + blockIdx.x) * 256 + tid;   // 0..65535
        erb[idx] = (__bf16)Er[idx];
        return;
    }
    const float* W = (z == 0) ? Wq : (z == 1 ? Wk : Wv);
    __bf16* dst = wt + (size_t)z * Dk * Dk;
    const int k0 = blockIdx.y * 64, n0 = blockIdx.x * 64;
    #pragma unroll
    for (int j = 0; j < 16; ++j) {
        int idx = tid + j * 256; int r = idx >> 6, c = idx & 63;
        tile[r][c] = W[(size_t)(k0 + r) * Dk + n0 + c];
    }
    __syncthreads();
    #pragma unroll
    for (int j = 0; j < 16; ++j) {
        int idx = tid + j * 256; int r = idx >> 6, c = idx & 63;
        dst[(size_t)(n0 + r) * Dk + k0 + c] = (__bf16)tile[c][r];   // Wt[n][k] = W[k][n]
    }
}

// ---------------- projections: m97-style 128x128 tile, BK=32, global_load_lds ----------------
__global__ __launch_bounds__(256) void proj_kernel(
    const float* __restrict__ Xq, const float* __restrict__ Xkv,
    const float* __restrict__ bq, const float* __restrict__ bk,
    const float* __restrict__ bv, const __bf16* __restrict__ wt,
    __bf16* __restrict__ qh, __bf16* __restrict__ kws, __bf16* __restrict__ vt)
{
    __shared__ __align__(16) float  Al[128 * 32];
    __shared__ __align__(16) __bf16 Bl[128 * 32];

    const int z = blockIdx.z;
    const float* X    = (z == 0) ? Xq : Xkv;
    const float* bias = (z == 0) ? bq : (z == 1 ? bk : bv);
    const __bf16* Wz  = wt + (size_t)z * Dk * Dk;

    const int m0   = blockIdx.x * 128;
    const int n0   = blockIdx.y * 128;
    const int tid  = threadIdx.x;
    const int lane = tid & 63;
    const int w    = tid >> 6;
    const int wr   = w >> 1, wc = w & 1;
    const int l15  = lane & 15;
    const int g    = lane >> 4;

    const float* asrc[4];
    int adst[4];
    #pragma unroll
    for (int i = 0; i < 4; ++i) {
        const int c = w * 4 + i;
        asrc[i] = X + (size_t)(m0 + c * 8 + (lane >> 3)) * Dk + (((lane & 7) ^ (lane >> 3)) << 2);
        adst[i] = c * 1024 + lane * 16;          // bytes
    }
    const __bf16* bsrc[2];
    int bdst[2];
    #pragma unroll
    for (int i = 0; i < 2; ++i) {
        const int c = w * 2 + i;
        bsrc[i] = Wz + (size_t)(n0 + c * 16 + (lane >> 2)) * Dk + (((lane & 3) ^ ((lane >> 3) & 3)) << 3);
        bdst[i] = c * 1024 + lane * 16;          // bytes
    }

    int aoff0[4], aoff1[4], boff[4];
    #pragma unroll
    for (int m = 0; m < 4; ++m) {
        const int row = wr * 64 + m * 16 + l15;          // row&7 == l15&7
        aoff0[m] = row * 128 + (((2 * g)     ^ (l15 & 7)) << 4);
        aoff1[m] = row * 128 + (((2 * g + 1) ^ (l15 & 7)) << 4);
    }
    #pragma unroll
    for (int n = 0; n < 4; ++n) {
        const int row = wc * 64 + n * 16 + l15;          // (row>>1)&3 == (l15>>1)&3
        boff[n] = row * 64 + ((g ^ ((l15 >> 1) & 3)) << 4);
    }

    const f32x4 fz = {0.f, 0.f, 0.f, 0.f};
    f32x4 acc[4][4];
    #pragma unroll
    for (int m = 0; m < 4; ++m)
        #pragma unroll
        for (int n = 0; n < 4; ++n) acc[m][n] = fz;

    const char* Alc = (const char*)Al;
    const char* Blc = (const char*)Bl;

    for (int ks = 0; ks < Dk / 32; ++ks) {
        #pragma unroll
        for (int i = 0; i < 4; ++i)
            load_lds16(asrc[i], (char*)Al + adst[i]);
        #pragma unroll
        for (int i = 0; i < 2; ++i)
            load_lds16(bsrc[i], (char*)Bl + bdst[i]);
        #pragma unroll
        for (int i = 0; i < 4; ++i) asrc[i] += 32;
        #pragma unroll
        for (int i = 0; i < 2; ++i) bsrc[i] += 32;
        __syncthreads();

        bf16x8 bf[4];
        #pragma unroll
        for (int n = 0; n < 4; ++n)
            bf[n] = *(const bf16x8*)(Blc + boff[n]);
        bf16x8 af[4];
        #pragma unroll
        for (int m = 0; m < 4; ++m) {
            f32x4 x0 = *(const f32x4*)(Alc + aoff0[m]);
            f32x4 x1 = *(const f32x4*)(Alc + aoff1[m]);
            bf16x8 a;
            a[0] = (__bf16)x0[0]; a[1] = (__bf16)x0[1]; a[2] = (__bf16)x0[2]; a[3] = (__bf16)x0[3];
            a[4] = (__bf16)x1[0]; a[5] = (__bf16)x1[1]; a[6] = (__bf16)x1[2]; a[7] = (__bf16)x1[3];
            af[m] = a;
        }

        #pragma unroll
        for (int m = 0; m < 4; ++m)
            #pragma unroll
            for (int n = 0; n < 4; ++n)
                acc[m][n] = MFMA_B16(af[m], bf[n], acc[m][n]);
        __syncthreads();
    }

    #pragma unroll
    for (int n = 0; n < 4; ++n) {
        const float bb = bias[n0 + wc * 64 + n * 16 + l15];
        #pragma unroll
        for (int m = 0; m < 4; ++m)
            #pragma unroll
            for (int r = 0; r < 4; ++r) acc[m][n][r] += bb;
    }

    const int b   = m0 >> 10;
    const int s0t = (m0 & 1023) + wr * 64;
    const int h   = (n0 + wc * 64) >> 6;

    if (z < 2) {
        __bf16* dst = (z == 0) ? qh : kws;
        const size_t rowbase = (size_t)(b * Hk + h) * Sk;
        #pragma unroll
        for (int m = 0; m < 4; ++m) {
            #pragma unroll
            for (int r = 0; r < 4; ++r) {
                const int s = s0t + m * 16 + g * 4 + r;
                __bf16* drow = dst + (rowbase + s) * DHk;
                #pragma unroll
                for (int n = 0; n < 4; ++n)
                    drow[n * 16 + l15] = (__bf16)acc[m][n][r];
            }
        }
    } else {
        const size_t hb = (size_t)(b * Hk + h) * DHk;
        #pragma unroll
        for (int m = 0; m < 4; ++m) {
            const int sb = s0t + m * 16 + g * 4;
            #pragma unroll
            for (int n = 0; n < 4; ++n) {
                const int dh = n * 16 + l15;
                bf16x4 pk;
                #pragma unroll
                for (int r = 0; r < 4; ++r) pk[r] = (__bf16)acc[m][n][r];
                *(bf16x4*)(vt + (hb + dh) * Sk + sb) = pk;
            }
        }
    }
}

// ---------------- fused causal attention with relative-position band ----------------
// Base = R13 exactly (best verified: 69 us attn; R14/R15/R16 variants all refuted
// and reverted). Single change this round: BALANCED QUARTILE STRIP MAP.
// R13's resources (VGPR 84 <= 128, LDS 40960 x 4 = exactly 160 KiB) allow 4
// blocks/CU co-resident, but heavy-first dispatch decays time-avg occupancy to
// ~25% (short-tail blocks finish early). With 1024 blocks round-robin over 256
// CUs, a CU receives lids {L, L+256, L+512, L+768} -> q16 in {q,q+4,q+8,q+12}
// (same rq, all four mq) -> strip map {15-r, 8+r, 7-r, r} sums to 30 strips =
// 34 tile-steps per CU, uniform finish. launch_bounds stays (256,3): it only
// GUARANTEES 3 blocks (cap 170 regs); 4 arise naturally from actual usage.
__global__ __launch_bounds__(256, 3) void attn_kernel(
    const __bf16* __restrict__ qh, const __bf16* __restrict__ kws,
    const __bf16* __restrict__ vt, const __bf16* __restrict__ erb,
    float* __restrict__ out)
{
    __shared__ __align__(16) __bf16 Kl[2][4096];     // [buf][64 s][64 dh], swizzled
    __shared__ __align__(16) __bf16 Vl[2][4096];     // [buf][64 dh][64 s], swizzled
    __shared__ __align__(16) __bf16 P_lds[4][16][64];// stride 64, XOR-swizzled

    const int tid  = threadIdx.x;
    const int lane = tid & 63;
    const int w    = tid >> 6;
    const int l15  = lane & 15;
    const int g    = lane >> 4;

    const int lid = blockIdx.x;          // 0..1023
    const int bh  = lid & 63;            // lid%8 == bh%8 -> one bh's blocks share an XCD
    const int q16 = lid >> 6;            // 0..15
    const int mq  = q16 >> 2, rq = q16 & 3;
    const int strip = (mq == 0) ? 15 - rq : (mq == 1) ? 8 + rq
                    : (mq == 2) ? 7 - rq : rq;       // per-CU balanced strip map
    const int ntw = strip + 1;
    const int sw  = strip * 64 + w * 16;

    const __bf16* kbase = kws + (size_t)bh * Sk * DHk;
    const __bf16* vbase = vt  + (size_t)bh * DHk * Sk;
    const __bf16* qbase = qh  + ((size_t)bh * Sk + sw) * DHk;

    __bf16 (*Pw)[64] = P_lds[w];

    // staging geometry: thread covers rows {trow, trow+32}, lds slot tslot,
    // source col-slot = tslot ^ (row&7)  (row&7 == trow&7)
    const int trow   = tid >> 3;
    const int tslot  = tid & 7;
    const int srcoff = (tslot ^ (trow & 7)) << 3;    // element offset (8 bf16 / slot)
    char* kd0 = (char*)Kl + tid * 16;                // dest byte == row*128 + slot*16
    char* vd0 = (char*)Vl + tid * 16;

    bf16x8 aq[2];
    aq[0] = *(const bf16x8*)(qbase + l15 * DHk + g * 8);
    aq[1] = *(const bf16x8*)(qbase + l15 * DHk + 32 + g * 8);

    const f32x4 fz = {0.f, 0.f, 0.f, 0.f};
    f32x4 O[4];
    float m_[4], l_[4];
    #pragma unroll
    for (int n = 0; n < 4; ++n) O[n] = fz;
    #pragma unroll
    for (int r = 0; r < 4; ++r) { m_[r] = -1e30f; l_[r] = 0.f; }

    const float SCL = 0.125f * 1.44269504088896f;    // 1/sqrt(DH) * log2(e)

    // ---- prologue: stage tile 0 into buffer 0 ----
    load_lds16(kbase + (size_t)trow * DHk + srcoff,        kd0);
    load_lds16(kbase + (size_t)(32 + trow) * DHk + srcoff, kd0 + 4096);
    load_lds16(vbase + (size_t)trow * Sk + srcoff,         vd0);
    load_lds16(vbase + (size_t)(32 + trow) * Sk + srcoff,  vd0 + 4096);
    __builtin_amdgcn_sched_barrier(0);
    asm volatile("s_waitcnt vmcnt(0)" ::: "memory");
    __builtin_amdgcn_sched_barrier(0);
    __builtin_amdgcn_s_barrier();
    __builtin_amdgcn_sched_barrier(0);

    for (int it = 0; it < ntw; ++it) {
        const int t0  = it * 64;
        const int cur = it & 1;

        // my stage ops for buf[cur] (issued one full iteration ago) retired
        __builtin_amdgcn_sched_barrier(0);
        asm volatile("s_waitcnt vmcnt(0)" ::: "memory");
        __builtin_amdgcn_sched_barrier(0);

        // ---- Er loads (10, register targets) — in flight ACROSS the barrier;
        //      latency hides under barrier-sync + QK^T ----
        const int jb = t0 - sw + 1008;           // 16-aligned, >= 0
        bf16x8 ec[10];
        #pragma unroll
        for (int kt = 0; kt < 2; ++kt)
            #pragma unroll
            for (int jj = 0; jj < 5; ++jj) {
                int jr = jb + jj * 16 + l15;
                jr = (jr > 1023) ? 1023 : jr;    // clamped rows are masked later
                ec[kt * 5 + jj] = *(const bf16x8*)(erb + (size_t)jr * DHk + kt * 32 + g * 8);
            }

        __builtin_amdgcn_sched_barrier(0);
        __builtin_amdgcn_s_barrier();            // single barrier: buf[cur] published,
        __builtin_amdgcn_sched_barrier(0);       // buf[cur^1] free for staging

        if (it + 1 < ntw) {
            const int t0n = t0 + 64;
            char* kd = kd0 + (cur ^ 1) * 8192;
            char* vd = vd0 + (cur ^ 1) * 8192;
            load_lds16(kbase + (size_t)(t0n + trow) * DHk + srcoff,      kd);
            load_lds16(kbase + (size_t)(t0n + 32 + trow) * DHk + srcoff, kd + 4096);
            load_lds16(vbase + (size_t)trow * Sk + t0n + srcoff,         vd);
            load_lds16(vbase + (size_t)(32 + trow) * Sk + t0n + srcoff,  vd + 4096);
        }

        const char* Kc = (const char*)Kl + cur * 8192;
        const char* Vc = (const char*)Vl + cur * 8192;

        // ---- QK^T from LDS (swizzled ds_read_b128) ----
        f32x4 sc[4];
        #pragma unroll
        for (int j = 0; j < 4; ++j) sc[j] = fz;
        #pragma unroll
        for (int kt = 0; kt < 2; ++kt) {
            bf16x8 kb[4];
            #pragma unroll
            for (int j = 0; j < 4; ++j)
                kb[j] = *(const bf16x8*)(Kc + (j * 16 + l15) * 128 + ((((kt << 2) | g) ^ (l15 & 7)) << 4));
            __builtin_amdgcn_s_setprio(1);
            #pragma unroll
            for (int j = 0; j < 4; ++j)
                sc[j] = MFMA_B16(aq[kt], kb[j], sc[j]);
            __builtin_amdgcn_s_setprio(0);
        }

        // ---- G = Q @ Er^T over the 80-wide band ----
        f32x4 gf[5];
        #pragma unroll
        for (int jj = 0; jj < 5; ++jj) gf[jj] = fz;
        __builtin_amdgcn_s_setprio(1);
        #pragma unroll
        for (int kt = 0; kt < 2; ++kt)
            #pragma unroll
            for (int jj = 0; jj < 5; ++jj)
                gf[jj] = MFMA_B16(aq[kt], ec[kt * 5 + jj], gf[jj]);
        __builtin_amdgcn_s_setprio(0);

        // ---- skew via shuffle + scale (exp2 domain) + causal mask ----
        #pragma unroll
        for (int r = 0; r < 4; ++r) {
            const int rr  = g * 4 + r;
            const int sft = 15 - rr;
            const int src = (g << 4) + ((l15 + sft) & 15);   // absolute lane in wave
            const bool hi = (l15 + sft) >= 16;
            float h[5];
            #pragma unroll
            for (int jj = 0; jj < 5; ++jj) h[jj] = __shfl(gf[jj][r], src);
            const int s = sw + rr;
            #pragma unroll
            for (int j = 0; j < 4; ++j) {
                float gval = hi ? h[j + 1] : h[j];
                float v = (sc[j][r] + gval) * SCL;
                int t = t0 + j * 16 + l15;
                sc[j][r] = (t > s) ? -1e30f : v;
            }
        }

        // ---- online softmax: DPP row reduces (VALU pipe), defer-max ----
        float mt[4];
        #pragma unroll
        for (int r = 0; r < 4; ++r)
            mt[r] = rmax16(fmaxf(fmaxf(sc[0][r], sc[1][r]), fmaxf(sc[2][r], sc[3][r])));

        bool grow = (mt[0] > m_[0] + 8.f) || (mt[1] > m_[1] + 8.f) ||
                    (mt[2] > m_[2] + 8.f) || (mt[3] > m_[3] + 8.f);
        if (__any(grow)) {
            #pragma unroll
            for (int r = 0; r < 4; ++r) {
                float mnew = fmaxf(m_[r], mt[r]);
                float scl  = exp2f(m_[r] - mnew);
                l_[r] *= scl;
                m_[r]  = mnew;
                #pragma unroll
                for (int n = 0; n < 4; ++n) O[n][r] *= scl;
            }
        }
        #pragma unroll
        for (int r = 0; r < 4; ++r) {
            float rs = 0.f;
            #pragma unroll
            for (int j = 0; j < 4; ++j) {
                float p = exp2f(sc[j][r] - m_[r]);
                sc[j][r] = p; rs += p;
            }
            l_[r] += rsum16(rs);
        }

        // ---- P -> LDS packed b32, XOR-swizzled stride-64 rows ----
        // logical (row, col c): byte = row*128 + ((slot(c)^(row&7))<<4) + (c&7)*2
        {
            const int p01 = l15 & 1;
            #pragma unroll
            for (int j = 0; j < 4; ++j) {
                const int slot = 2 * j + (l15 >> 3);
                #pragma unroll
                for (int h2 = 0; h2 < 2; ++h2) {
                    float a0 = sc[j][h2];
                    float a2 = sc[j][h2 + 2];
                    float b0 = dppf<0xB1>(a0);       // partner lane's row-h2 value
                    float b2 = dppf<0xB1>(a2);       // partner lane's row-h2+2 value
                    float lo = p01 ? b2 : a0;
                    float hi = p01 ? a2 : b0;
                    unsigned wd = pk_bf16(lo, hi);
                    const int row = g * 4 + h2 + (p01 ? 2 : 0);
                    const int byteoff = row * 128 + (((slot ^ (row & 7)) << 4) | ((l15 & 6) << 1));
                    *(u32a*)((char*)Pw + byteoff) = wd;
                }
            }
        }
        asm volatile("" ::: "memory");
        __builtin_amdgcn_sched_barrier(0);

        // ---- PV (V from LDS, swizzled ds_read_b128; P read with same XOR) ----
        __builtin_amdgcn_s_setprio(1);
        #pragma unroll
        for (int kt = 0; kt < 2; ++kt) {
            bf16x8 pa = *(const bf16x8*)((const char*)Pw + l15 * 128 +
                                         ((((kt << 2) | g) ^ (l15 & 7)) << 4));
            #pragma unroll
            for (int n = 0; n < 4; ++n) {
                bf16x8 vbf = *(const bf16x8*)(Vc + (n * 16 + l15) * 128 + ((((kt << 2) | g) ^ (l15 & 7)) << 4));
                O[n] = MFMA_B16(pa, vbf, O[n]);
            }
        }
        __builtin_amdgcn_s_setprio(0);
    }

    // ---- normalize + write out [b][s][h*64+dh] ----
    const int b = bh >> 4, h = bh & 15;
    float* obase = out + ((size_t)b * Sk + sw) * Dk + h * DHk;
    #pragma unroll
    for (int r = 0; r < 4; ++r) {
        float inv = 1.f / l_[r];
        #pragma unroll
        for (int n = 0; n < 4; ++n)
            obase[(size_t)(g * 4 + r) * Dk + n * 16 + l15] = O[n][r] * inv;
    }
}

extern "C" void kernel_launch(void* const* d_in, const int* in_sizes, int n_in,
                              void* d_out, int out_size, void* d_ws, size_t ws_size,
                              hipStream_t stream)
{
    const float* q  = (const float*)d_in[0];
    const float* kv = (const float*)d_in[1];
    const float* Wq = (const float*)d_in[2];
    const float* bq = (const float*)d_in[3];
    const float* Wk = (const float*)d_in[4];
    const float* bk = (const float*)d_in[5];
    const float* Wv = (const float*)d_in[6];
    const float* bv = (const float*)d_in[7];
    const float* Er = (const float*)d_in[8];
    float* out = (float*)d_out;

    if (ws_size < WS_ELEMS * sizeof(__bf16)) return;
    __bf16* ws  = (__bf16*)d_ws;
    __bf16* qh  = ws + QH_OFF;
    __bf16* kws = ws + K_OFF;
    __bf16* vt  = ws + VT_OFF;
    __bf16* wt  = ws + WT_OFF;
    __bf16* erb = ws + ER_OFF;

    prep_kernel<<<dim3(16, 16, 4), 256, 0, stream>>>(Wq, Wk, Wv, Er, wt, erb);
    proj_kernel<<<dim3(32, 8, 3), 256, 0, stream>>>(q, kv, bq, bk, bv, wt, qh, kws, vt);
    attn_kernel<<<dim3(1024), 256, 0, stream>>>(qh, kws, vt, erb, out);
}